// Round 4
// baseline (133.359 us; speedup 1.0000x reference)
//
#include <hip/hip_runtime.h>

// GraphSAGE layer: out = relu(h @ Ws^T + (scatter_mean(h,src,dst)) @ Wn^T + b)
// N=50000, E=800000, dim 128.
// R17: scatter parallelism. Accounting across R13-R16 shows dur_us carries a
//      fixed ~43us harness fill + K_A~45 + gather~26 + gemm~12. K_A's cost is
//      98 scatter blocks (8192 edges each) grinding LDS sort on 98 CUs while
//      the rest idle. Single change vs R13 anchor: scatter blocks 8192->2048
//      edges (98->391 blocks, 2 edges/thread), spreading the sort over all
//      CUs. K_B/K4 verbatim from the 126.96us R13 anchor.
constexpr int N_NODES_C = 50000;
constexpr int N_EDGES_C = 800000;
constexpr int DIM_C     = 128;

constexpr int NBKT  = 196;    // (50000+255)>>8
constexpr int CAP   = 8192;   // bucket capacity; mean fill 4096, sd ~64
constexpr int EPB_S = 2048;   // edges per scatter block (R17: was 8192)
constexpr int NB_SCAT  = 391; // (800000+2047)/2048
constexpr int NB_WCAST = 2;   // W-cast blocks: one per matrix
constexpr int NB_CASTK = 391; // h-cast blocks: 1024 thr x 16 elems, guarded

constexpr int SUBS    = 4;    // csr_gather sub-blocks per bucket
constexpr int NSUB    = 64;   // nodes per sub-block
constexpr int CAP_SUB = 2048; // sub-block edge capacity; mean 1024, sd ~32

typedef __attribute__((ext_vector_type(8))) short short8;  // 8 bf16, 4 VGPRs
typedef __attribute__((ext_vector_type(4))) float f32x4;
typedef __attribute__((ext_vector_type(2))) float f32x2;

// Workspace layout (bytes), ~38.7 MB used:
constexpr size_t OFF_HB   = 0;                                   // ushort[N][128]
constexpr size_t OFF_ACC  = (size_t)N_NODES_C * DIM_C * 2;       // 12,800,000
constexpr size_t OFF_PK   = OFF_ACC + (size_t)N_NODES_C * DIM_C * 2;  // 25,600,000
constexpr size_t OFF_GC   = OFF_PK + (size_t)NBKT * CAP * 4;     // 32,022,528
constexpr size_t OFF_WB   = OFF_GC + 1024;                       // ushort[2][128][128]
constexpr size_t OFF_H8   = OFF_WB + 2 * DIM_C * DIM_C * 2;      // uchar[N][128] fp8

// round-to-nearest-even f32 -> bf16 bits (finite inputs only)
static __device__ __forceinline__ ushort f2bf(float f) {
  unsigned u = __float_as_uint(f);
  return (ushort)((u + 0x7FFFu + ((u >> 16) & 1u)) >> 16);
}
static __device__ __forceinline__ unsigned pack2(float a, float b) {
  return (unsigned)f2bf(a) | ((unsigned)f2bf(b) << 16);
}
// 4 floats -> 4 packed OCP e4m3 bytes (HW cvt, RNE)
static __device__ __forceinline__ unsigned pk_fp8x4(float4 a) {
  unsigned u = __builtin_amdgcn_cvt_pk_fp8_f32(a.x, a.y, 0u, false);
  return __builtin_amdgcn_cvt_pk_fp8_f32(a.z, a.w, u, true);
}

// --------------------------------------------------------------------------
// K_A: fused bucket scatter + cast(W) + cast(h -> bf16 AND fp8).
// Scatter block (2048 edges, 2/thread): LDS hist over 196 buckets -> wave-0
// scan -> one global atomicAdd per nonzero bin (bulk reserve) -> LDS
// counting sort -> write-out 4 buckets/wave x 16 lanes (mean run ~10).
// LDS ~11 KB; 391 scatter blocks spread over all CUs.
// --------------------------------------------------------------------------
__global__ __launch_bounds__(1024) void sage_cast_bucket(
    const float* __restrict__ h, ushort* __restrict__ hb,
    unsigned char* __restrict__ h8,
    const float* __restrict__ Wself, const float* __restrict__ Wneigh,
    ushort* __restrict__ wb,
    const int* __restrict__ src, const int* __restrict__ dst,
    int* __restrict__ gcur, unsigned* __restrict__ packed)
{
  const int b = blockIdx.x;
  const int t = threadIdx.x;
  if (b >= NB_SCAT) {
    if (b < NB_SCAT + NB_WCAST) {
      int m = b - NB_SCAT;                    // 0: Wself, 1: Wneigh
      const float* sp = m ? Wneigh : Wself;
      ushort* dp = wb + (size_t)m * DIM_C * DIM_C;
      size_t i = (size_t)t * 16;              // 1024*16 = 16384 exactly
      float4 a0 = *reinterpret_cast<const float4*>(sp + i);
      float4 a1 = *reinterpret_cast<const float4*>(sp + i + 4);
      float4 a2 = *reinterpret_cast<const float4*>(sp + i + 8);
      float4 a3 = *reinterpret_cast<const float4*>(sp + i + 12);
      uint4 o0, o1;
      o0.x = pack2(a0.x, a0.y); o0.y = pack2(a0.z, a0.w);
      o0.z = pack2(a1.x, a1.y); o0.w = pack2(a1.z, a1.w);
      o1.x = pack2(a2.x, a2.y); o1.y = pack2(a2.z, a2.w);
      o1.z = pack2(a3.x, a3.y); o1.w = pack2(a3.z, a3.w);
      *reinterpret_cast<uint4*>(dp + i)     = o0;
      *reinterpret_cast<uint4*>(dp + i + 8) = o1;
    } else {
      int tid = (b - NB_SCAT - NB_WCAST) * 1024 + t;
      if (tid >= 400000) return;              // 400000*16 = 6.4M elems
      size_t i = (size_t)tid * 16;
      float4 a0 = *reinterpret_cast<const float4*>(h + i);
      float4 a1 = *reinterpret_cast<const float4*>(h + i + 4);
      float4 a2 = *reinterpret_cast<const float4*>(h + i + 8);
      float4 a3 = *reinterpret_cast<const float4*>(h + i + 12);
      uint4 o0, o1;
      o0.x = pack2(a0.x, a0.y); o0.y = pack2(a0.z, a0.w);
      o0.z = pack2(a1.x, a1.y); o0.w = pack2(a1.z, a1.w);
      o1.x = pack2(a2.x, a2.y); o1.y = pack2(a2.z, a2.w);
      o1.z = pack2(a3.x, a3.y); o1.w = pack2(a3.z, a3.w);
      *reinterpret_cast<uint4*>(hb + i)     = o0;
      *reinterpret_cast<uint4*>(hb + i + 8) = o1;
      uint4 q;                                 // 16 fp8 bytes
      q.x = pk_fp8x4(a0); q.y = pk_fp8x4(a1);
      q.z = pk_fp8x4(a2); q.w = pk_fp8x4(a3);
      *reinterpret_cast<uint4*>(h8 + i) = q;
    }
    return;
  }

  __shared__ int      bh[256];       // per-bucket count (padded for scan)
  __shared__ int      excl[256];
  __shared__ int      curb[NBKT];
  __shared__ int      bofsG[NBKT];   // reserved base within bucket region
  __shared__ unsigned sorted[EPB_S]; // 8 KB

  const int e0 = b * EPB_S + t * 2;
  const bool l0 = (e0 < N_EDGES_C);          // E%2==0: int2 valid when base<E

  if (t < 256) bh[t] = 0;
  __syncthreads();

  int2 da, sa;
  if (l0) {
    da = *reinterpret_cast<const int2*>(dst + e0);
    sa = *reinterpret_cast<const int2*>(src + e0);
    atomicAdd(&bh[da.x >> 8], 1);
    atomicAdd(&bh[da.y >> 8], 1);
  }
  __syncthreads();

  // exclusive scan of bh[256] by wave 0 (4 bins/lane)
  if (t < 64) {
    int base = t * 4;
    int h0 = bh[base], h1 = bh[base + 1], h2 = bh[base + 2], h3 = bh[base + 3];
    int s = h0 + h1 + h2 + h3;
    int x = s;
#pragma unroll
    for (int d = 1; d < 64; d <<= 1) {
      int y = __shfl_up(x, d, 64);
      if (t >= d) x += y;
    }
    int ex = x - s;
    excl[base]     = ex;
    excl[base + 1] = ex + h0;
    excl[base + 2] = ex + h0 + h1;
    excl[base + 3] = ex + h0 + h1 + h2;
  }
  __syncthreads();

  if (t < NBKT) {
    curb[t]  = excl[t];
    bofsG[t] = (bh[t] > 0) ? atomicAdd(&gcur[t], bh[t]) : 0;
  }
  __syncthreads();

#define PLACE(dd, ss)                                            \
  do {                                                           \
    int p_ = atomicAdd(&curb[(dd) >> 8], 1);                     \
    sorted[p_] = ((unsigned)((dd) & 255) << 16) | (unsigned)(ss);\
  } while (0)
  if (l0) { PLACE(da.x, sa.x); PLACE(da.y, sa.y); }
#undef PLACE
  __syncthreads();

  // write-out: 4 buckets per wave, 16 lanes each (mean run ~10)
  const int w    = t >> 6;
  const int lane = t & 63;
  const int sbk  = lane >> 4;
  const int sl   = lane & 15;
  for (int k = w * 4 + sbk; k < NBKT; k += 64) {
    int len = bh[k];
    if (len == 0) continue;
    int gb  = bofsG[k];
    if (gb + len > CAP) len = CAP - gb;      // statistically unreachable
    int lb  = excl[k];
    unsigned* outp = packed + (size_t)k * CAP + gb;
    for (int off = sl; off < len; off += 16)
      outp[off] = sorted[lb + off];
  }
}

// --------------------------------------------------------------------------
// K_B: per-sub-bucket counting sort + gather-mean, fp8 rows (128B/row).
// Block (bucket b, sub s) owns node-ids rid in [s*64, s*64+64). 784x256.
// Gather: 8 lanes/node x 16 fp8 (uint4, 16B) per lane; 16 f32 accumulators.
// 1/deg from hist (== input deg by construction). Verbatim R13 anchor.
// --------------------------------------------------------------------------
__global__ __launch_bounds__(256) void sage_csr_gather(
    const unsigned* __restrict__ packed, const int* __restrict__ gcur,
    const unsigned char* __restrict__ h8, ushort* __restrict__ accb)
{
  __shared__ int    hist[NSUB];
  __shared__ int    excl_s[NSUB];
  __shared__ int    curb[NSUB];
  __shared__ ushort esrc_l[CAP_SUB];   // 4 KB

  const int b   = blockIdx.x >> 2;     // bucket
  const int sub = blockIdx.x & 3;
  const int rlo = sub * NSUB;
  const int t = threadIdx.x;
  const int count = min(gcur[b], CAP);
  const unsigned* pk = packed + (size_t)b * CAP;
  const int nvec = count >> 2;
  const int ntail = count & 3;

  if (t < NSUB) hist[t] = 0;
  __syncthreads();

  // pass 1: histogram of our rid range (vectorized scan, L2-hot)
  for (int g = t; g < nvec; g += 256) {
    uint4 w4 = *reinterpret_cast<const uint4*>(pk + g * 4);
    int r;
    r = (int)(w4.x >> 16) - rlo; if ((unsigned)r < (unsigned)NSUB) atomicAdd(&hist[r], 1);
    r = (int)(w4.y >> 16) - rlo; if ((unsigned)r < (unsigned)NSUB) atomicAdd(&hist[r], 1);
    r = (int)(w4.z >> 16) - rlo; if ((unsigned)r < (unsigned)NSUB) atomicAdd(&hist[r], 1);
    r = (int)(w4.w >> 16) - rlo; if ((unsigned)r < (unsigned)NSUB) atomicAdd(&hist[r], 1);
  }
  if (t < ntail) {
    int r = (int)(pk[nvec * 4 + t] >> 16) - rlo;
    if ((unsigned)r < (unsigned)NSUB) atomicAdd(&hist[r], 1);
  }
  __syncthreads();

  // exclusive scan of hist[64] by wave 0 (1 bin per lane)
  if (t < 64) {
    int v = hist[t];
    int x = v;
#pragma unroll
    for (int d = 1; d < 64; d <<= 1) {
      int y = __shfl_up(x, d, 64);
      if (t >= d) x += y;
    }
    excl_s[t] = x - v;
    curb[t]   = x - v;
  }
  __syncthreads();

  // pass 2: filtered placement
  for (int g = t; g < nvec; g += 256) {
    uint4 w4 = *reinterpret_cast<const uint4*>(pk + g * 4);
    unsigned ww[4] = {w4.x, w4.y, w4.z, w4.w};
#pragma unroll
    for (int j = 0; j < 4; j++) {
      int r = (int)(ww[j] >> 16) - rlo;
      if ((unsigned)r < (unsigned)NSUB) {
        int p = atomicAdd(&curb[r], 1);
        esrc_l[p] = (ushort)(ww[j] & 0xFFFFu);
      }
    }
  }
  if (t < ntail) {
    unsigned wv = pk[nvec * 4 + t];
    int r = (int)(wv >> 16) - rlo;
    if ((unsigned)r < (unsigned)NSUB) {
      int p = atomicAdd(&curb[r], 1);
      esrc_l[p] = (ushort)(wv & 0xFFFFu);
    }
  }
  __syncthreads();

  // gather: 2 rounds x 32 nodes; 8 lanes per node, 16 fp8 per lane (uint4).
  const int c = (t & 7) << 4;
#pragma unroll
  for (int rd = 0; rd < 2; rd++) {
    int lr = rd * 32 + (t >> 3);     // local rid 0..63
    int n = (b << 8) + rlo + lr;
    if (n >= N_NODES_C) continue;
    int begin = excl_s[lr];
    int cnt   = hist[lr];
    int end   = begin + cnt;

    float s[16];
#pragma unroll
    for (int j = 0; j < 16; j++) s[j] = 0.f;

#define ACCD(wd, o)                                                \
    do {                                                           \
      f32x2 p_;                                                    \
      p_ = __builtin_amdgcn_cvt_pk_f32_fp8((wd), false);           \
      s[(o)]     += p_.x; s[(o) + 1] += p_.y;                      \
      p_ = __builtin_amdgcn_cvt_pk_f32_fp8((wd), true);            \
      s[(o) + 2] += p_.x; s[(o) + 3] += p_.y;                      \
    } while (0)
#define ACC16(u)                                                   \
    do { ACCD((u).x, 0); ACCD((u).y, 4); ACCD((u).z, 8); ACCD((u).w, 12); } while (0)

    int i = begin;
    for (; i + 3 < end; i += 4) {
      int e0 = esrc_l[i], e1 = esrc_l[i + 1], e2 = esrc_l[i + 2], e3 = esrc_l[i + 3];
      uint4 a  = *reinterpret_cast<const uint4*>(h8 + (size_t)e0 * DIM_C + c);
      uint4 bb = *reinterpret_cast<const uint4*>(h8 + (size_t)e1 * DIM_C + c);
      uint4 d  = *reinterpret_cast<const uint4*>(h8 + (size_t)e2 * DIM_C + c);
      uint4 f  = *reinterpret_cast<const uint4*>(h8 + (size_t)e3 * DIM_C + c);
      ACC16(a); ACC16(bb); ACC16(d); ACC16(f);
    }
    for (; i < end; i++) {
      int e0 = esrc_l[i];
      uint4 a = *reinterpret_cast<const uint4*>(h8 + (size_t)e0 * DIM_C + c);
      ACC16(a);
    }
#undef ACC16
#undef ACCD

    float id = 1.0f / (float)max(cnt, 1);   // == 1/deg[n] by construction
    uint4 o0, o1;
    o0.x = pack2(s[0]  * id, s[1]  * id);
    o0.y = pack2(s[2]  * id, s[3]  * id);
    o0.z = pack2(s[4]  * id, s[5]  * id);
    o0.w = pack2(s[6]  * id, s[7]  * id);
    o1.x = pack2(s[8]  * id, s[9]  * id);
    o1.y = pack2(s[10] * id, s[11] * id);
    o1.z = pack2(s[12] * id, s[13] * id);
    o1.w = pack2(s[14] * id, s[15] * id);
    *reinterpret_cast<uint4*>(accb + (size_t)n * DIM_C + c)     = o0;
    *reinterpret_cast<uint4*>(accb + (size_t)n * DIM_C + c + 8) = o1;
  }
}

// --------------------------------------------------------------------------
// K4: fused bf16 MFMA GEMM, K=256 (k<128 from h_bf16, k>=128 from acc_bf16).
// Block = 256 thr (4 waves), 128 rows/block. W staged from pre-cast bf16
// global into padded LDS (uint4 copies).
// Layouts (m89/m91-verified): A[m=lane&15][k=quad*8+j];
// B from W[n][k] with n=lane&15, k=quad*8+j; C/D col=lane&15, row=quad*4+reg.
// --------------------------------------------------------------------------
__global__ __launch_bounds__(256) void sage_gemm_mfma(
    const ushort* __restrict__ hb, const ushort* __restrict__ accb,
    const ushort* __restrict__ wb, const float* __restrict__ bias,
    float* __restrict__ out)
{
  __shared__ ushort Bl[DIM_C][256 + 8];   // 67,584 B
  __shared__ float  bias_l[DIM_C];

  const int t = threadIdx.x;

  for (int idx = t; idx < DIM_C * 16; idx += 256) {
    int n  = idx >> 4;
    int c8 = (idx & 15) << 3;
    uint4 w0 = *reinterpret_cast<const uint4*>(wb + (size_t)n * DIM_C + c8);
    uint4 w1 = *reinterpret_cast<const uint4*>(wb + (size_t)(DIM_C + n) * DIM_C + c8);
    *reinterpret_cast<uint4*>(&Bl[n][c8])       = w0;
    *reinterpret_cast<uint4*>(&Bl[n][128 + c8]) = w1;
  }
  if (t < DIM_C) bias_l[t] = bias[t];
  __syncthreads();

  const int lane = t & 63;
  const int w    = t >> 6;
  const int am   = lane & 15;
  const int q    = lane >> 4;
  const int mb   = blockIdx.x * 128;
  const int m0   = mb + w * 16;        // row-tile 0
  const int m1   = mb + 64 + w * 16;   // row-tile 1

  int r0 = m0 + am; if (r0 >= N_NODES_C) r0 = N_NODES_C - 1;
  int r1 = m1 + am; if (r1 >= N_NODES_C) r1 = N_NODES_C - 1;
  const ushort* aph0 = hb   + (size_t)r0 * DIM_C + q * 8;
  const ushort* apa0 = accb + (size_t)r0 * DIM_C + q * 8;
  const ushort* aph1 = hb   + (size_t)r1 * DIM_C + q * 8;
  const ushort* apa1 = accb + (size_t)r1 * DIM_C + q * 8;

  f32x4 acc[2][8];
#pragma unroll
  for (int i = 0; i < 2; i++)
#pragma unroll
    for (int nt = 0; nt < 8; nt++) acc[i][nt] = (f32x4){0.f, 0.f, 0.f, 0.f};

#pragma unroll
  for (int ks = 0; ks < 4; ks++) {
    short8 a0 = *reinterpret_cast<const short8*>(aph0 + ks * 32);
    short8 a1 = *reinterpret_cast<const short8*>(aph1 + ks * 32);
#pragma unroll
    for (int nt = 0; nt < 8; nt++) {
      short8 bf = *reinterpret_cast<const short8*>(&Bl[nt * 16 + am][ks * 32 + q * 8]);
      acc[0][nt] = __builtin_amdgcn_mfma_f32_16x16x32_bf16(a0, bf, acc[0][nt], 0, 0, 0);
      acc[1][nt] = __builtin_amdgcn_mfma_f32_16x16x32_bf16(a1, bf, acc[1][nt], 0, 0, 0);
    }
  }
#pragma unroll
  for (int ks = 0; ks < 4; ks++) {
    short8 a0 = *reinterpret_cast<const short8*>(apa0 + ks * 32);
    short8 a1 = *reinterpret_cast<const short8*>(apa1 + ks * 32);
#pragma unroll
    for (int nt = 0; nt < 8; nt++) {
      short8 bf = *reinterpret_cast<const short8*>(&Bl[nt * 16 + am][128 + ks * 32 + q * 8]);
      acc[0][nt] = __builtin_amdgcn_mfma_f32_16x16x32_bf16(a0, bf, acc[0][nt], 0, 0, 0);
      acc[1][nt] = __builtin_amdgcn_mfma_f32_16x16x32_bf16(a1, bf, acc[1][nt], 0, 0, 0);
    }
  }

#pragma unroll
  for (int i = 0; i < 2; i++) {
    int mt = (i == 0) ? m0 : m1;
#pragma unroll
    for (int nt = 0; nt < 8; nt++) {
      int col = nt * 16 + am;
      float bv = bias_l[col];
#pragma unroll
      for (int rr = 0; rr < 4; rr++) {
        int row = mt + q * 4 + rr;
        if (row < N_NODES_C) {
          float v = acc[i][nt][rr] + bv;
          out[(size_t)row * DIM_C + col] = fmaxf(v, 0.f);
        }
      }
    }
  }
}

// --------------------------------------------------------------------------
extern "C" void kernel_launch(void* const* d_in, const int* in_sizes, int n_in,
                              void* d_out, int out_size, void* d_ws, size_t ws_size,
                              hipStream_t stream) {
  const float* h      = (const float*)d_in[0];
  const int*   src    = (const int*)d_in[1];
  const int*   dst    = (const int*)d_in[2];
  const float* Wself  = (const float*)d_in[4];
  const float* Wneigh = (const float*)d_in[5];
  const float* bias   = (const float*)d_in[6];
  float*       out    = (float*)d_out;

  char* ws = (char*)d_ws;
  ushort*        hb     = (ushort*)(ws + OFF_HB);
  ushort*        accb   = (ushort*)(ws + OFF_ACC);
  unsigned*      packed = (unsigned*)(ws + OFF_PK);
  int*           gcur   = (int*)(ws + OFF_GC);
  ushort*        wb     = (ushort*)(ws + OFF_WB);
  unsigned char* h8     = (unsigned char*)(ws + OFF_H8);

  // Zero the 196 bucket cursors only (784 B); all else fully overwritten.
  hipMemsetAsync(gcur, 0, NBKT * sizeof(int), stream);

  sage_cast_bucket<<<NB_SCAT + NB_WCAST + NB_CASTK, 1024, 0, stream>>>(
      h, hb, h8, Wself, Wneigh, wb, src, dst, gcur, packed);
  sage_csr_gather <<<NBKT * SUBS, 256, 0, stream>>>(packed, gcur, h8, accb);
  sage_gemm_mfma  <<<(N_NODES_C + 127) / 128, 256, 0, stream>>>(hb, accb, wb,
                                                                bias, out);
}

// Round 5
// 128.464 us; speedup vs baseline: 1.0381x; 1.0381x over previous
//
#include <hip/hip_runtime.h>

// GraphSAGE layer: out = relu(h @ Ws^T + (scatter_mean(h,src,dst)) @ Wn^T + b)
// N=50000, E=800000, dim 128.
// R18: L2-resident gather. Budget re-derivation across R13-R17 shows the
//      controllable sum is only ~42us (K_A~5, K_B~25, K4~12) atop a ~85us
//      harness-fixed fill term. K_B is L2-THRASH-bound: random reads over a
//      6.4MB h8 table > 4MB per-XCD L2. Change: h8 stored as [2][N][64]
//      column halves; gather runs two half-passes (4 lanes/node, 64 nodes at
//      once) so the per-pass working set is 3.2MB < L2/XCD. Same loads,
//      bytes, and per-column FP order. All else verbatim R13 anchor.
constexpr int N_NODES_C = 50000;
constexpr int N_EDGES_C = 800000;
constexpr int DIM_C     = 128;

constexpr int NBKT  = 196;    // (50000+255)>>8
constexpr int CAP   = 8192;   // bucket capacity; mean fill 4096, sd ~64
constexpr int EPB_S = 8192;   // edges per scatter block
constexpr int NB_SCAT  = 98;  // (800000+8191)/8192
constexpr int NB_WCAST = 2;   // W-cast blocks: one per matrix
constexpr int NB_CASTK = 391; // h-cast blocks: 1024 thr x 16 elems, guarded

constexpr int SUBS    = 4;    // csr_gather sub-blocks per bucket
constexpr int NSUB    = 64;   // nodes per sub-block
constexpr int CAP_SUB = 2048; // sub-block edge capacity; mean 1024, sd ~32
constexpr int HHALF   = 64;   // fp8 columns per half

typedef __attribute__((ext_vector_type(8))) short short8;  // 8 bf16, 4 VGPRs
typedef __attribute__((ext_vector_type(4))) float f32x4;
typedef __attribute__((ext_vector_type(2))) float f32x2;

// Workspace layout (bytes), ~38.7 MB used:
constexpr size_t OFF_HB   = 0;                                   // ushort[N][128]
constexpr size_t OFF_ACC  = (size_t)N_NODES_C * DIM_C * 2;       // 12,800,000
constexpr size_t OFF_PK   = OFF_ACC + (size_t)N_NODES_C * DIM_C * 2;  // 25,600,000
constexpr size_t OFF_GC   = OFF_PK + (size_t)NBKT * CAP * 4;     // 32,022,528
constexpr size_t OFF_WB   = OFF_GC + 1024;                       // ushort[2][128][128]
constexpr size_t OFF_H8   = OFF_WB + 2 * DIM_C * DIM_C * 2;      // uchar[2][N][64] fp8

// round-to-nearest-even f32 -> bf16 bits (finite inputs only)
static __device__ __forceinline__ ushort f2bf(float f) {
  unsigned u = __float_as_uint(f);
  return (ushort)((u + 0x7FFFu + ((u >> 16) & 1u)) >> 16);
}
static __device__ __forceinline__ unsigned pack2(float a, float b) {
  return (unsigned)f2bf(a) | ((unsigned)f2bf(b) << 16);
}
// 4 floats -> 4 packed OCP e4m3 bytes (HW cvt, RNE)
static __device__ __forceinline__ unsigned pk_fp8x4(float4 a) {
  unsigned u = __builtin_amdgcn_cvt_pk_fp8_f32(a.x, a.y, 0u, false);
  return __builtin_amdgcn_cvt_pk_fp8_f32(a.z, a.w, u, true);
}

// --------------------------------------------------------------------------
// K_A: fused bucket scatter + cast(W) + cast(h -> bf16 AND fp8-halves).
// Scatter block (8192 edges): LDS hist over 196 buckets -> wave-0 scan ->
// one global atomicAdd per nonzero bin (bulk reserve) -> LDS counting sort
// -> per-run coalesced burst write-out. Verbatim R13 except h8 half-layout.
// --------------------------------------------------------------------------
__global__ __launch_bounds__(1024) void sage_cast_bucket(
    const float* __restrict__ h, ushort* __restrict__ hb,
    unsigned char* __restrict__ h8,
    const float* __restrict__ Wself, const float* __restrict__ Wneigh,
    ushort* __restrict__ wb,
    const int* __restrict__ src, const int* __restrict__ dst,
    int* __restrict__ gcur, unsigned* __restrict__ packed)
{
  const int b = blockIdx.x;
  const int t = threadIdx.x;
  if (b >= NB_SCAT) {
    if (b < NB_SCAT + NB_WCAST) {
      int m = b - NB_SCAT;                    // 0: Wself, 1: Wneigh
      const float* sp = m ? Wneigh : Wself;
      ushort* dp = wb + (size_t)m * DIM_C * DIM_C;
      size_t i = (size_t)t * 16;              // 1024*16 = 16384 exactly
      float4 a0 = *reinterpret_cast<const float4*>(sp + i);
      float4 a1 = *reinterpret_cast<const float4*>(sp + i + 4);
      float4 a2 = *reinterpret_cast<const float4*>(sp + i + 8);
      float4 a3 = *reinterpret_cast<const float4*>(sp + i + 12);
      uint4 o0, o1;
      o0.x = pack2(a0.x, a0.y); o0.y = pack2(a0.z, a0.w);
      o0.z = pack2(a1.x, a1.y); o0.w = pack2(a1.z, a1.w);
      o1.x = pack2(a2.x, a2.y); o1.y = pack2(a2.z, a2.w);
      o1.z = pack2(a3.x, a3.y); o1.w = pack2(a3.z, a3.w);
      *reinterpret_cast<uint4*>(dp + i)     = o0;
      *reinterpret_cast<uint4*>(dp + i + 8) = o1;
    } else {
      int tid = (b - NB_SCAT - NB_WCAST) * 1024 + t;
      if (tid >= 400000) return;              // 400000*16 = 6.4M elems
      size_t i = (size_t)tid * 16;
      float4 a0 = *reinterpret_cast<const float4*>(h + i);
      float4 a1 = *reinterpret_cast<const float4*>(h + i + 4);
      float4 a2 = *reinterpret_cast<const float4*>(h + i + 8);
      float4 a3 = *reinterpret_cast<const float4*>(h + i + 12);
      uint4 o0, o1;
      o0.x = pack2(a0.x, a0.y); o0.y = pack2(a0.z, a0.w);
      o0.z = pack2(a1.x, a1.y); o0.w = pack2(a1.z, a1.w);
      o1.x = pack2(a2.x, a2.y); o1.y = pack2(a2.z, a2.w);
      o1.z = pack2(a3.x, a3.y); o1.w = pack2(a3.z, a3.w);
      *reinterpret_cast<uint4*>(hb + i)     = o0;
      *reinterpret_cast<uint4*>(hb + i + 8) = o1;
      uint4 q;                                 // 16 fp8 bytes
      q.x = pk_fp8x4(a0); q.y = pk_fp8x4(a1);
      q.z = pk_fp8x4(a2); q.w = pk_fp8x4(a3);
      // half-split layout: [2][N][64]; 16B chunk lies entirely in one half
      size_t row  = i >> 7;
      int    col  = (int)(i & 127);
      size_t half = (size_t)(col >> 6);
      *reinterpret_cast<uint4*>(h8 + half * ((size_t)N_NODES_C * HHALF)
                                + row * HHALF + (col & 63)) = q;
    }
    return;
  }

  __shared__ int      bh[256];       // per-bucket count (padded for scan)
  __shared__ int      excl[256];
  __shared__ int      curb[NBKT];
  __shared__ int      bofsG[NBKT];   // reserved base within bucket region
  __shared__ unsigned sorted[EPB_S]; // 32 KB

  const int e0 = b * EPB_S + t * 8;
  const bool l0 = (e0     < N_EDGES_C);      // E%4==0: int4 valid when base<E
  const bool l1 = (e0 + 4 < N_EDGES_C);

  if (t < 256) bh[t] = 0;
  __syncthreads();

  int4 da, db, sa, sb;
  if (l0) {
    da = *reinterpret_cast<const int4*>(dst + e0);
    sa = *reinterpret_cast<const int4*>(src + e0);
    atomicAdd(&bh[da.x >> 8], 1); atomicAdd(&bh[da.y >> 8], 1);
    atomicAdd(&bh[da.z >> 8], 1); atomicAdd(&bh[da.w >> 8], 1);
  }
  if (l1) {
    db = *reinterpret_cast<const int4*>(dst + e0 + 4);
    sb = *reinterpret_cast<const int4*>(src + e0 + 4);
    atomicAdd(&bh[db.x >> 8], 1); atomicAdd(&bh[db.y >> 8], 1);
    atomicAdd(&bh[db.z >> 8], 1); atomicAdd(&bh[db.w >> 8], 1);
  }
  __syncthreads();

  // exclusive scan of bh[256] by wave 0 (4 bins/lane)
  if (t < 64) {
    int base = t * 4;
    int h0 = bh[base], h1 = bh[base + 1], h2 = bh[base + 2], h3 = bh[base + 3];
    int s = h0 + h1 + h2 + h3;
    int x = s;
#pragma unroll
    for (int d = 1; d < 64; d <<= 1) {
      int y = __shfl_up(x, d, 64);
      if (t >= d) x += y;
    }
    int ex = x - s;
    excl[base]     = ex;
    excl[base + 1] = ex + h0;
    excl[base + 2] = ex + h0 + h1;
    excl[base + 3] = ex + h0 + h1 + h2;
  }
  __syncthreads();

  if (t < NBKT) {
    curb[t]  = excl[t];
    bofsG[t] = (bh[t] > 0) ? atomicAdd(&gcur[t], bh[t]) : 0;
  }
  __syncthreads();

#define PLACE(dd, ss)                                            \
  do {                                                           \
    int p_ = atomicAdd(&curb[(dd) >> 8], 1);                     \
    sorted[p_] = ((unsigned)((dd) & 255) << 16) | (unsigned)(ss);\
  } while (0)
  if (l0) { PLACE(da.x, sa.x); PLACE(da.y, sa.y); PLACE(da.z, sa.z); PLACE(da.w, sa.w); }
  if (l1) { PLACE(db.x, sb.x); PLACE(db.y, sb.y); PLACE(db.z, sb.z); PLACE(db.w, sb.w); }
#undef PLACE
  __syncthreads();

  // coalesced burst write-out: wave w owns buckets w, w+16, ...
  const int w    = t >> 6;
  const int lane = t & 63;
  for (int k = w; k < NBKT; k += 16) {
    int len = bh[k];
    int gb  = bofsG[k];
    if (gb + len > CAP) len = CAP - gb;      // statistically unreachable
    int lb  = excl[k];
    unsigned* outp = packed + (size_t)k * CAP + gb;
    for (int off = lane; off < len; off += 64)
      outp[off] = sorted[lb + off];
  }
}

// --------------------------------------------------------------------------
// K_B: per-sub-bucket counting sort + gather-mean, fp8 half-rows (64B each).
// Block (bucket b, sub s) owns node-ids rid in [s*64, s*64+64). 784x256.
// Gather: two half-column passes; per pass 4 lanes/node x 16 fp8 (uint4),
// all 64 nodes at once. Per-pass chip working set = 3.2MB < 4MB L2/XCD.
// 1/deg from hist (== input deg by construction).
// --------------------------------------------------------------------------
__global__ __launch_bounds__(256) void sage_csr_gather(
    const unsigned* __restrict__ packed, const int* __restrict__ gcur,
    const unsigned char* __restrict__ h8, ushort* __restrict__ accb)
{
  __shared__ int    hist[NSUB];
  __shared__ int    excl_s[NSUB];
  __shared__ int    curb[NSUB];
  __shared__ ushort esrc_l[CAP_SUB];   // 4 KB

  const int b   = blockIdx.x >> 2;     // bucket
  const int sub = blockIdx.x & 3;
  const int rlo = sub * NSUB;
  const int t = threadIdx.x;
  const int count = min(gcur[b], CAP);
  const unsigned* pk = packed + (size_t)b * CAP;
  const int nvec = count >> 2;
  const int ntail = count & 3;

  if (t < NSUB) hist[t] = 0;
  __syncthreads();

  // pass 1: histogram of our rid range (vectorized scan, L2-hot)
  for (int g = t; g < nvec; g += 256) {
    uint4 w4 = *reinterpret_cast<const uint4*>(pk + g * 4);
    int r;
    r = (int)(w4.x >> 16) - rlo; if ((unsigned)r < (unsigned)NSUB) atomicAdd(&hist[r], 1);
    r = (int)(w4.y >> 16) - rlo; if ((unsigned)r < (unsigned)NSUB) atomicAdd(&hist[r], 1);
    r = (int)(w4.z >> 16) - rlo; if ((unsigned)r < (unsigned)NSUB) atomicAdd(&hist[r], 1);
    r = (int)(w4.w >> 16) - rlo; if ((unsigned)r < (unsigned)NSUB) atomicAdd(&hist[r], 1);
  }
  if (t < ntail) {
    int r = (int)(pk[nvec * 4 + t] >> 16) - rlo;
    if ((unsigned)r < (unsigned)NSUB) atomicAdd(&hist[r], 1);
  }
  __syncthreads();

  // exclusive scan of hist[64] by wave 0 (1 bin per lane)
  if (t < 64) {
    int v = hist[t];
    int x = v;
#pragma unroll
    for (int d = 1; d < 64; d <<= 1) {
      int y = __shfl_up(x, d, 64);
      if (t >= d) x += y;
    }
    excl_s[t] = x - v;
    curb[t]   = x - v;
  }
  __syncthreads();

  // pass 2: filtered placement
  for (int g = t; g < nvec; g += 256) {
    uint4 w4 = *reinterpret_cast<const uint4*>(pk + g * 4);
    unsigned ww[4] = {w4.x, w4.y, w4.z, w4.w};
#pragma unroll
    for (int j = 0; j < 4; j++) {
      int r = (int)(ww[j] >> 16) - rlo;
      if ((unsigned)r < (unsigned)NSUB) {
        int p = atomicAdd(&curb[r], 1);
        esrc_l[p] = (ushort)(ww[j] & 0xFFFFu);
      }
    }
  }
  if (t < ntail) {
    unsigned wv = pk[nvec * 4 + t];
    int r = (int)(wv >> 16) - rlo;
    if ((unsigned)r < (unsigned)NSUB) {
      int p = atomicAdd(&curb[r], 1);
      esrc_l[p] = (ushort)(wv & 0xFFFFu);
    }
  }
  __syncthreads();

  // gather: two half-column passes; 4 lanes/node, 64 nodes at once.
  const int lq = t & 3;              // which 16B of the 64B half
  const int lr = t >> 2;             // local rid 0..63
  const int n  = (b << 8) + rlo + lr;
  const bool valid = (n < N_NODES_C);
  const int begin = excl_s[lr];
  const int cnt   = hist[lr];
  const int end   = begin + cnt;
  const float id  = 1.0f / (float)max(cnt, 1);  // == 1/deg[n]

#define ACCD(wd, o)                                                \
  do {                                                             \
    f32x2 p_;                                                      \
    p_ = __builtin_amdgcn_cvt_pk_f32_fp8((wd), false);             \
    s[(o)]     += p_.x; s[(o) + 1] += p_.y;                        \
    p_ = __builtin_amdgcn_cvt_pk_f32_fp8((wd), true);              \
    s[(o) + 2] += p_.x; s[(o) + 3] += p_.y;                        \
  } while (0)
#define ACC16(u)                                                   \
  do { ACCD((u).x, 0); ACCD((u).y, 4); ACCD((u).z, 8); ACCD((u).w, 12); } while (0)

#pragma unroll
  for (int half = 0; half < 2; half++) {
    const unsigned char* hp = h8 + (size_t)half * ((size_t)N_NODES_C * HHALF)
                              + lq * 16;
    float s[16];
#pragma unroll
    for (int j = 0; j < 16; j++) s[j] = 0.f;

    if (valid) {
      int i = begin;
      for (; i + 3 < end; i += 4) {
        int e0 = esrc_l[i], e1 = esrc_l[i + 1], e2 = esrc_l[i + 2], e3 = esrc_l[i + 3];
        uint4 a  = *reinterpret_cast<const uint4*>(hp + (size_t)e0 * HHALF);
        uint4 bb = *reinterpret_cast<const uint4*>(hp + (size_t)e1 * HHALF);
        uint4 d  = *reinterpret_cast<const uint4*>(hp + (size_t)e2 * HHALF);
        uint4 f  = *reinterpret_cast<const uint4*>(hp + (size_t)e3 * HHALF);
        ACC16(a); ACC16(bb); ACC16(d); ACC16(f);
      }
      for (; i < end; i++) {
        int e0 = esrc_l[i];
        uint4 a = *reinterpret_cast<const uint4*>(hp + (size_t)e0 * HHALF);
        ACC16(a);
      }

      uint4 o0, o1;
      o0.x = pack2(s[0]  * id, s[1]  * id);
      o0.y = pack2(s[2]  * id, s[3]  * id);
      o0.z = pack2(s[4]  * id, s[5]  * id);
      o0.w = pack2(s[6]  * id, s[7]  * id);
      o1.x = pack2(s[8]  * id, s[9]  * id);
      o1.y = pack2(s[10] * id, s[11] * id);
      o1.z = pack2(s[12] * id, s[13] * id);
      o1.w = pack2(s[14] * id, s[15] * id);
      ushort* ap = accb + (size_t)n * DIM_C + half * HHALF + lq * 16;
      *reinterpret_cast<uint4*>(ap)     = o0;
      *reinterpret_cast<uint4*>(ap + 8) = o1;
    }
  }
#undef ACC16
#undef ACCD
}

// --------------------------------------------------------------------------
// K4: fused bf16 MFMA GEMM, K=256 (k<128 from h_bf16, k>=128 from acc_bf16).
// Block = 256 thr (4 waves), 128 rows/block. W staged from pre-cast bf16
// global into padded LDS (uint4 copies). Verbatim R13.
// Layouts (m89/m91-verified): A[m=lane&15][k=quad*8+j];
// B from W[n][k] with n=lane&15, k=quad*8+j; C/D col=lane&15, row=quad*4+reg.
// --------------------------------------------------------------------------
__global__ __launch_bounds__(256) void sage_gemm_mfma(
    const ushort* __restrict__ hb, const ushort* __restrict__ accb,
    const ushort* __restrict__ wb, const float* __restrict__ bias,
    float* __restrict__ out)
{
  __shared__ ushort Bl[DIM_C][256 + 8];   // 67,584 B
  __shared__ float  bias_l[DIM_C];

  const int t = threadIdx.x;

  for (int idx = t; idx < DIM_C * 16; idx += 256) {
    int n  = idx >> 4;
    int c8 = (idx & 15) << 3;
    uint4 w0 = *reinterpret_cast<const uint4*>(wb + (size_t)n * DIM_C + c8);
    uint4 w1 = *reinterpret_cast<const uint4*>(wb + (size_t)(DIM_C + n) * DIM_C + c8);
    *reinterpret_cast<uint4*>(&Bl[n][c8])       = w0;
    *reinterpret_cast<uint4*>(&Bl[n][128 + c8]) = w1;
  }
  if (t < DIM_C) bias_l[t] = bias[t];
  __syncthreads();

  const int lane = t & 63;
  const int w    = t >> 6;
  const int am   = lane & 15;
  const int q    = lane >> 4;
  const int mb   = blockIdx.x * 128;
  const int m0   = mb + w * 16;        // row-tile 0
  const int m1   = mb + 64 + w * 16;   // row-tile 1

  int r0 = m0 + am; if (r0 >= N_NODES_C) r0 = N_NODES_C - 1;
  int r1 = m1 + am; if (r1 >= N_NODES_C) r1 = N_NODES_C - 1;
  const ushort* aph0 = hb   + (size_t)r0 * DIM_C + q * 8;
  const ushort* apa0 = accb + (size_t)r0 * DIM_C + q * 8;
  const ushort* aph1 = hb   + (size_t)r1 * DIM_C + q * 8;
  const ushort* apa1 = accb + (size_t)r1 * DIM_C + q * 8;

  f32x4 acc[2][8];
#pragma unroll
  for (int i = 0; i < 2; i++)
#pragma unroll
    for (int nt = 0; nt < 8; nt++) acc[i][nt] = (f32x4){0.f, 0.f, 0.f, 0.f};

#pragma unroll
  for (int ks = 0; ks < 4; ks++) {
    short8 a0 = *reinterpret_cast<const short8*>(aph0 + ks * 32);
    short8 a1 = *reinterpret_cast<const short8*>(aph1 + ks * 32);
#pragma unroll
    for (int nt = 0; nt < 8; nt++) {
      short8 bf = *reinterpret_cast<const short8*>(&Bl[nt * 16 + am][ks * 32 + q * 8]);
      acc[0][nt] = __builtin_amdgcn_mfma_f32_16x16x32_bf16(a0, bf, acc[0][nt], 0, 0, 0);
      acc[1][nt] = __builtin_amdgcn_mfma_f32_16x16x32_bf16(a1, bf, acc[1][nt], 0, 0, 0);
    }
  }
#pragma unroll
  for (int ks = 0; ks < 4; ks++) {
    short8 a0 = *reinterpret_cast<const short8*>(apa0 + ks * 32);
    short8 a1 = *reinterpret_cast<const short8*>(apa1 + ks * 32);
#pragma unroll
    for (int nt = 0; nt < 8; nt++) {
      short8 bf = *reinterpret_cast<const short8*>(&Bl[nt * 16 + am][128 + ks * 32 + q * 8]);
      acc[0][nt] = __builtin_amdgcn_mfma_f32_16x16x32_bf16(a0, bf, acc[0][nt], 0, 0, 0);
      acc[1][nt] = __builtin_amdgcn_mfma_f32_16x16x32_bf16(a1, bf, acc[1][nt], 0, 0, 0);
    }
  }

#pragma unroll
  for (int i = 0; i < 2; i++) {
    int mt = (i == 0) ? m0 : m1;
#pragma unroll
    for (int nt = 0; nt < 8; nt++) {
      int col = nt * 16 + am;
      float bv = bias_l[col];
#pragma unroll
      for (int rr = 0; rr < 4; rr++) {
        int row = mt + q * 4 + rr;
        if (row < N_NODES_C) {
          float v = acc[i][nt][rr] + bv;
          out[(size_t)row * DIM_C + col] = fmaxf(v, 0.f);
        }
      }
    }
  }
}

// --------------------------------------------------------------------------
extern "C" void kernel_launch(void* const* d_in, const int* in_sizes, int n_in,
                              void* d_out, int out_size, void* d_ws, size_t ws_size,
                              hipStream_t stream) {
  const float* h      = (const float*)d_in[0];
  const int*   src    = (const int*)d_in[1];
  const int*   dst    = (const int*)d_in[2];
  const float* Wself  = (const float*)d_in[4];
  const float* Wneigh = (const float*)d_in[5];
  const float* bias   = (const float*)d_in[6];
  float*       out    = (float*)d_out;

  char* ws = (char*)d_ws;
  ushort*        hb     = (ushort*)(ws + OFF_HB);
  ushort*        accb   = (ushort*)(ws + OFF_ACC);
  unsigned*      packed = (unsigned*)(ws + OFF_PK);
  int*           gcur   = (int*)(ws + OFF_GC);
  ushort*        wb     = (ushort*)(ws + OFF_WB);
  unsigned char* h8     = (unsigned char*)(ws + OFF_H8);

  // Zero the 196 bucket cursors only (784 B); all else fully overwritten.
  hipMemsetAsync(gcur, 0, NBKT * sizeof(int), stream);

  sage_cast_bucket<<<NB_SCAT + NB_WCAST + NB_CASTK, 1024, 0, stream>>>(
      h, hb, h8, Wself, Wneigh, wb, src, dst, gcur, packed);
  sage_csr_gather <<<NBKT * SUBS, 256, 0, stream>>>(packed, gcur, h8, accb);
  sage_gemm_mfma  <<<(N_NODES_C + 127) / 128, 256, 0, stream>>>(hb, accb, wb,
                                                                bias, out);
}